// Round 15
// baseline (2023.546 us; speedup 1.0000x reference)
//
#include <hip/hip_runtime.h>
#include <math.h>

typedef int i32x4 __attribute__((ext_vector_type(4)));
typedef float f32x4 __attribute__((ext_vector_type(4)));
typedef float f32x2 __attribute__((ext_vector_type(2)));

#define QMAXF 127.0f
#define EPSQ 1e-8f

__device__ __forceinline__ void gl_lds16(const void* g, void* l) {
  __builtin_amdgcn_global_load_lds(
      (const __attribute__((address_space(1))) unsigned int*)g,
      (__attribute__((address_space(3))) unsigned int*)l, 16, 0, 0);
}
__device__ __forceinline__ void gl_lds4(const void* g, void* l) {
  __builtin_amdgcn_global_load_lds(
      (const __attribute__((address_space(1))) unsigned int*)g,
      (__attribute__((address_space(3))) unsigned int*)l, 4, 0, 0);
}

// Group-of-128 symmetric int8 quant: fp32 in -> int8 q + transposed scales.
// Exact reference math in fp32; f32x4 loads, group per 32-lane half-wave.
__global__ __launch_bounds__(256)
void qdq8(const float* __restrict__ in, char* __restrict__ q,
          float* __restrict__ sT, long n_groups, int gpr, int R) {
  long grp = (long)blockIdx.x * 8 + (threadIdx.x >> 5);
  if (grp >= n_groups) return;
  int hl = threadIdx.x & 31;
  long base = grp * 128 + hl * 4;
  f32x4 v = *(const f32x4*)(in + base);
  float m = fmaxf(fmaxf(fabsf(v.x), fabsf(v.y)), fmaxf(fabsf(v.z), fabsf(v.w)));
#pragma unroll
  for (int off = 16; off; off >>= 1) m = fmaxf(m, __shfl_xor(m, off));
  float s = fmaxf(m / QMAXF, EPSQ);
  int q0 = (int)fminf(fmaxf(rintf(v.x / s), -QMAXF), QMAXF);
  int q1 = (int)fminf(fmaxf(rintf(v.y / s), -QMAXF), QMAXF);
  int q2 = (int)fminf(fmaxf(rintf(v.z / s), -QMAXF), QMAXF);
  int q3 = (int)fminf(fmaxf(rintf(v.w / s), -QMAXF), QMAXF);
  *(int*)(q + base) = (q0 & 0xff) | ((q1 & 0xff) << 8) |
                      ((q2 & 0xff) << 16) | ((q3 & 0xff) << 24);
  if (hl == 0) {
    long row = grp / gpr;
    long gc = grp - row * gpr;
    sT[gc * (long)R + row] = s;
  }
}

// ---------------------------------------------------------------------------
// v15 gu: break the 256-unified-reg / 2-waves-per-SIMD cap.
// 128x128 tile, single-buffered (r5 skeleton: stage -> sync -> compute ->
// sync), 512 thr / 8 SINGLE-DTYPE waves: wid 0-3 gate, 4-7 up, each owning a
// 64x64 sub-tile of ONE dtype -> acc = 64 f32; af i-halved -> ~116 regs/wave
// -> __launch_bounds__(512,4) gives 4 waves/SIMD AND (LDS 68.6KB) 2
// co-resident blocks whose barrier phases interleave.
// SwiGLU fused via 64KB LDS gate-exchange overlaying the dead tiles after
// the K-loop (r12-proven). G4 XOR swizzle both sides; exact int32 MFMA +
// fp32 rescale; tile cols = 128 = one quant group -> fused hidden quant.
// ---------------------------------------------------------------------------

// gu LDS (bytes): tiles A@0(16K) BG@16384 BU@32768 -- union with gexch
// (128x128 f32 = 64K) used after the K-loop. scales @65536 (1536B: sSa/sSg/
// sSu 128 f32 each). rmx@67072 (2x128 f32). rs@68096 (512). Total 68608.
#define GU_SC 65536
#define GU_RMX 67072
#define GU_RS 68096
#define GU_LDS 68608

__global__ __launch_bounds__(512, 4)
void gemm_gu_i8(const char* __restrict__ Aq, const char* __restrict__ Bg,
                const char* __restrict__ Bu,
                const float* __restrict__ sAT, const float* __restrict__ sGT,
                const float* __restrict__ sUT,
                char* __restrict__ Hq, float* __restrict__ sHT,
                int M, int N, int K, int NBN) {
  extern __shared__ __align__(16) char smem[];
  const int tid = threadIdx.x;
  const int lane = tid & 63;
  const int wid = tid >> 6;
  const int dw = wid & 3;
  const bool is_up = wid >= 4;
  const int wr = (dw >> 1) * 64, wc = (dw & 1) * 64;
  const int l15 = lane & 15, l16 = lane >> 4;

  const int nwg = gridDim.x;
  const int wg = ((int)blockIdx.x & 7) * (nwg >> 3) + ((int)blockIdx.x >> 3);
  const long m0 = (long)(wg / NBN) * 128;
  const long n0 = (long)(wg % NBN) * 128;

  // staging: each 16KB tile = 1024 x 16B chunks; thread stages c = tid, tid+512
  // (rows rowS, rowS+64; row&7 invariant under +64 -> same swizzled offset).
  const long rowS = tid >> 3;
  const int offS = ((tid & 7) * 16) ^ ((int)(rowS & 7) << 4);
  const long kstr = 64L * K;
  const char* gA0 = Aq + (m0 + rowS) * K + offS;
  const char* gG0 = Bg + (n0 + rowS) * K + offS;
  const char* gU0 = Bu + (n0 + rowS) * K + offS;

  const int rdSwz = (l15 & 7) << 4;
  const int colK0 = (l16 * 16) ^ rdSwz;
  const int colK1 = (64 + l16 * 16) ^ rdSwz;

  f32x4 acc[4][4];
#pragma unroll
  for (int i = 0; i < 4; i++)
#pragma unroll
    for (int j = 0; j < 4; j++) acc[i][j] = (f32x4){0.f, 0.f, 0.f, 0.f};
  const i32x4 iz = {0, 0, 0, 0};
  const int KG = K >> 7;

  for (int g = 0; g < KG; ++g) {
    const long kb = (long)g << 7;
    gl_lds16(gA0 + kb, smem + tid * 16);
    gl_lds16(gA0 + kb + kstr, smem + (tid + 512) * 16);
    gl_lds16(gG0 + kb, smem + 16384 + tid * 16);
    gl_lds16(gG0 + kb + kstr, smem + 16384 + (tid + 512) * 16);
    gl_lds16(gU0 + kb, smem + 32768 + tid * 16);
    gl_lds16(gU0 + kb + kstr, smem + 32768 + (tid + 512) * 16);
    // scales (contiguous transposed layout; wave-uniform LDS dst, m104)
    char* sc8 = smem + GU_SC;
    if (wid == 0)      gl_lds4(sAT + (long)g * M + m0 + lane,      sc8);
    else if (wid == 1) gl_lds4(sAT + (long)g * M + m0 + 64 + lane, sc8 + 256);
    else if (wid == 2) gl_lds4(sGT + (long)g * N + n0 + lane,      sc8 + 512);
    else if (wid == 3) gl_lds4(sGT + (long)g * N + n0 + 64 + lane, sc8 + 768);
    else if (wid == 4) gl_lds4(sUT + (long)g * N + n0 + lane,      sc8 + 1024);
    else if (wid == 5) gl_lds4(sUT + (long)g * N + n0 + 64 + lane, sc8 + 1280);
    __syncthreads();

    const char* tbB = smem + (is_up ? 32768 : 16384);
    const float* sc = (const float*)(smem + GU_SC);
    const float* scB = sc + (is_up ? 256 : 128);

#pragma unroll
    for (int h = 0; h < 2; ++h) {  // i = h*2 + ii (af i-halved: 16 live regs)
      i32x4 af[2][2];
      f32x4 sa4[2];
#pragma unroll
      for (int ii = 0; ii < 2; ii++) {
        const int i = h * 2 + ii;
        const int rb = (wr + i * 16 + l15) * 128;
        af[ii][0] = *(const i32x4*)(smem + rb + colK0);
        af[ii][1] = *(const i32x4*)(smem + rb + colK1);
        sa4[ii] = *(const f32x4*)(sc + wr + i * 16 + l16 * 4);
      }
#pragma unroll
      for (int j = 0; j < 4; j++) {
        const int rbB = (wc + j * 16 + l15) * 128;
        i32x4 bf0 = *(const i32x4*)(tbB + rbB + colK0);
        i32x4 bf1 = *(const i32x4*)(tbB + rbB + colK1);
        float sb = scB[wc + j * 16 + l15];
#pragma unroll
        for (int ii = 0; ii < 2; ii++) {
          i32x4 t = __builtin_amdgcn_mfma_i32_16x16x64_i8(af[ii][0], bf0, iz, 0, 0, 0);
          t = __builtin_amdgcn_mfma_i32_16x16x64_i8(af[ii][1], bf1, t, 0, 0, 0);
          acc[h * 2 + ii][j] += (sa4[ii] * sb) * __builtin_convertvector(t, f32x4);
        }
      }
    }
    __syncthreads();
  }

  // ---- epilogue: gate waves publish via LDS; up waves apply SwiGLU,
  // per-row (tile = one 128-col group) max -> s, quantize, write out.
  float* gexch = (float*)smem;  // [128][128] f32 overlaying dead tiles
  if (!is_up) {
#pragma unroll
    for (int i = 0; i < 4; i++)
#pragma unroll
      for (int j = 0; j < 4; j++)
#pragma unroll
        for (int r = 0; r < 4; r++)
          gexch[(wr + i * 16 + l16 * 4 + r) * 128 + wc + j * 16 + l15] = acc[i][j][r];
  }
  __syncthreads();
  float* rmx = (float*)(smem + GU_RMX);  // [2][128]
  float* rs = (float*)(smem + GU_RS);    // [128]
  if (is_up) {
    float pm[4][4];
#pragma unroll
    for (int i = 0; i < 4; i++)
#pragma unroll
      for (int r = 0; r < 4; r++) pm[i][r] = 0.f;
#pragma unroll
    for (int i = 0; i < 4; i++)
#pragma unroll
      for (int j = 0; j < 4; j++)
#pragma unroll
        for (int r = 0; r < 4; r++) {
          int row = wr + i * 16 + l16 * 4 + r;
          int col = wc + j * 16 + l15;
          float gv = gexch[row * 128 + col];
          float h = gv / (1.f + expf(-gv)) * acc[i][j][r];
          acc[i][j][r] = h;
          pm[i][r] = fmaxf(pm[i][r], fabsf(h));
        }
#pragma unroll
    for (int i = 0; i < 4; i++)
#pragma unroll
      for (int r = 0; r < 4; r++) {
        pm[i][r] = fmaxf(pm[i][r], __shfl_xor(pm[i][r], 1));
        pm[i][r] = fmaxf(pm[i][r], __shfl_xor(pm[i][r], 2));
        pm[i][r] = fmaxf(pm[i][r], __shfl_xor(pm[i][r], 4));
        pm[i][r] = fmaxf(pm[i][r], __shfl_xor(pm[i][r], 8));
      }
#pragma unroll
    for (int i = 0; i < 4; i++)
#pragma unroll
      for (int r = 0; r < 4; r++)
        if (l15 == i * 4 + r)
          rmx[(dw & 1) * 128 + wr + i * 16 + l16 * 4 + r] = pm[i][r];
  }
  __syncthreads();
  if (tid < 128) {
    float mx = fmaxf(rmx[tid], rmx[128 + tid]);
    float s = fmaxf(mx / QMAXF, EPSQ);
    rs[tid] = s;
    sHT[(n0 >> 7) * (long)M + m0 + tid] = s;
  }
  __syncthreads();
  char* qb = smem;  // 128x128 i8, gexch dead (h held in up-wave acc)
  if (is_up) {
#pragma unroll
    for (int i = 0; i < 4; i++) {
      f32x4 sr = *(const f32x4*)(rs + wr + i * 16 + l16 * 4);
#pragma unroll
      for (int j = 0; j < 4; j++)
#pragma unroll
        for (int r = 0; r < 4; r++) {
          float qv = fminf(fmaxf(rintf(acc[i][j][r] / sr[r]), -QMAXF), QMAXF);
          qb[(wr + i * 16 + l16 * 4 + r) * 128 + wc + j * 16 + l15] = (char)(int)qv;
        }
    }
  }
  __syncthreads();
  {
    long row = tid >> 2;
    int off = (tid & 3) * 32;
    const i32x4* src = (const i32x4*)(qb + row * 128 + off);
    i32x4* dst = (i32x4*)(Hq + (m0 + row) * N + n0 + off);
    dst[0] = src[0];
    dst[1] = src[1];
  }
}

// dn LDS map: buf b at b*49152: A@0 (32K), B@32768 (16K).
// scales @98304 + b*1536: sSa(1024) sSb@+1024(512). Total 101376.
#define DN_SC 98304
#define DN_LDS 101376

// Down GEMM: fp32 out = dequant(A_i8) . dequant(B_i8)^T with exact int cores.
// (r14 version: 256x128 dbuf + depth-1 pipelined rescale.)
__global__ __launch_bounds__(512, 2)
void gemm_dn_i8(const char* __restrict__ Aq, const char* __restrict__ Bq,
                const float* __restrict__ sAT, const float* __restrict__ sBT,
                float* __restrict__ C, int M, int N, int K, int NBN) {
  extern __shared__ __align__(16) char smem[];
  const int tid = threadIdx.x;
  const int lane = tid & 63;
  const int wid = tid >> 6;
  const int wm = wid >> 1, wn = wid & 1;
  const int wr = wm * 64, wc = wn * 64;
  const int l15 = lane & 15, l16 = lane >> 4;

  const int nwg = gridDim.x;
  const int wg = ((int)blockIdx.x & 7) * (nwg >> 3) + ((int)blockIdx.x >> 3);
  const long m0 = (long)(wg / NBN) * 256;
  const long n0 = (long)(wg % NBN) * 128;

  const long rowS = tid >> 3;
  const int offS = ((tid & 7) * 16) ^ ((int)(rowS & 7) << 4);
  const long kstr = 64L * K;
  const char* gA0 = Aq + (m0 + rowS) * K + offS;
  const char* gB0 = Bq + (n0 + rowS) * K + offS;

  const int rdSwz = (l15 & 7) << 4;
  const int colK0 = (l16 * 16) ^ rdSwz;
  const int colK1 = (64 + l16 * 16) ^ rdSwz;

  f32x4 acc[4][4];
#pragma unroll
  for (int i = 0; i < 4; i++)
#pragma unroll
    for (int j = 0; j < 4; j++) acc[i][j] = (f32x4){0.f, 0.f, 0.f, 0.f};
  const i32x4 iz = {0, 0, 0, 0};
  const int KG = K >> 7;

#define DN_STAGE(gg, bb)                                                      \
  {                                                                           \
    const long kb = (long)(gg) << 7;                                          \
    char* tb = smem + (bb) * 49152;                                           \
    _Pragma("unroll") for (int k = 0; k < 4; k++)                             \
        gl_lds16(gA0 + kb + k * kstr, tb + (tid + 512 * k) * 16);             \
    _Pragma("unroll") for (int k = 0; k < 2; k++)                             \
        gl_lds16(gB0 + kb + k * kstr, tb + 32768 + (tid + 512 * k) * 16);     \
    char* sc = smem + DN_SC + (bb) * 1536;                                    \
    if (wid < 4) {                                                            \
      gl_lds4(sAT + (long)(gg) * M + m0 + tid, sc + wid * 256);               \
    } else if (wid < 6) {                                                     \
      gl_lds4(sBT + (long)(gg) * N + n0 + (tid - 256), sc + 1024 + (wid - 4) * 256); \
    }                                                                         \
  }

  DN_STAGE(0, 0);
  __syncthreads();

  for (int g = 0; g < KG; ++g) {
    const int cb = g & 1;
    if (g + 1 < KG) DN_STAGE(g + 1, cb ^ 1);

    const char* tb = smem + cb * 49152;
    const float* sc = (const float*)(smem + DN_SC + cb * 1536);

    i32x4 af[4][2];
#pragma unroll
    for (int i = 0; i < 4; i++) {
      const int rb = (wr + i * 16 + l15) * 128;
      af[i][0] = *(const i32x4*)(tb + rb + colK0);
      af[i][1] = *(const i32x4*)(tb + rb + colK1);
    }
    f32x4 sa4[4];
#pragma unroll
    for (int i = 0; i < 4; i++)
      sa4[i] = *(const f32x4*)(sc + wr + i * 16 + l16 * 4);

    i32x4 tP;
    f32x4 msP;
#pragma unroll
    for (int j = 0; j < 4; j++) {
      const int rbB = (wc + j * 16 + l15) * 128;
      i32x4 bf0 = *(const i32x4*)(tb + 32768 + rbB + colK0);
      i32x4 bf1 = *(const i32x4*)(tb + 32768 + rbB + colK1);
      float sb = sc[256 + wc + j * 16 + l15];
#pragma unroll
      for (int i = 0; i < 4; i++) {
        i32x4 t = __builtin_amdgcn_mfma_i32_16x16x64_i8(af[i][0], bf0, iz, 0, 0, 0);
        t = __builtin_amdgcn_mfma_i32_16x16x64_i8(af[i][1], bf1, t, 0, 0, 0);
        if (j > 0 || i > 0) {
          const int pf = j * 4 + i - 1;
          const int ip = pf & 3, jp = pf >> 2;
          acc[ip][jp] += msP * __builtin_convertvector(tP, f32x4);
        }
        tP = t;
        msP = sa4[i] * sb;
      }
    }
    acc[3][3] += msP * __builtin_convertvector(tP, f32x4);
    __syncthreads();
  }

#pragma unroll
  for (int i = 0; i < 4; i++)
#pragma unroll
    for (int j = 0; j < 4; j++)
#pragma unroll
      for (int r = 0; r < 4; r++) {
        long row = m0 + wr + i * 16 + l16 * 4 + r;
        long col = n0 + wc + j * 16 + l15;
        C[row * N + col] = acc[i][j][r];
      }
}

extern "C" void kernel_launch(void* const* d_in, const int* in_sizes, int n_in,
                              void* d_out, int out_size, void* d_ws, size_t ws_size,
                              hipStream_t stream) {
  (void)n_in; (void)out_size;
  const float* x  = (const float*)d_in[0];
  const float* wg = (const float*)d_in[1];
  const float* wu = (const float*)d_in[2];
  const float* wd = (const float*)d_in[3];
  float* out = (float*)d_out;

  const long H = 4096;
  const long M = in_sizes[0] / H;   // 4096 (B*S)
  const long I = in_sizes[1] / H;   // 11008
  const long GH = H >> 7;           // 32
  const long GI = I >> 7;           // 86

  char* ws = (char*)d_ws;
  size_t off = 0;
  char* xq  = ws + off; off += (size_t)(M * H);
  char* wgq = ws + off; off += (size_t)(I * H);
  char* wuq = ws + off; off += (size_t)(I * H);
  char* wdq = ws + off; off += (size_t)(H * I);
  char* hq  = ws + off; off += (size_t)(M * I);
  float* s_x = (float*)(ws + off); off += (size_t)(GH * M) * 4;
  float* s_g = (float*)(ws + off); off += (size_t)(GH * I) * 4;
  float* s_u = (float*)(ws + off); off += (size_t)(GH * I) * 4;
  float* s_d = (float*)(ws + off); off += (size_t)(GI * H) * 4;
  float* s_h = (float*)(ws + off); off += (size_t)(GI * M) * 4;
  if (ws_size < off) return;

  hipFuncSetAttribute((const void*)gemm_gu_i8,
                      hipFuncAttributeMaxDynamicSharedMemorySize, GU_LDS);
  hipFuncSetAttribute((const void*)gemm_dn_i8,
                      hipFuncAttributeMaxDynamicSharedMemorySize, DN_LDS);

  // 1) int8 group-quant of inputs/weights (q + transposed scales)
  {
    long ng;
    ng = M * H / 128;
    qdq8<<<dim3((unsigned)((ng + 7) / 8)), dim3(256), 0, stream>>>(x, xq, s_x, ng, (int)GH, (int)M);
    ng = I * H / 128;
    qdq8<<<dim3((unsigned)((ng + 7) / 8)), dim3(256), 0, stream>>>(wg, wgq, s_g, ng, (int)GH, (int)I);
    qdq8<<<dim3((unsigned)((ng + 7) / 8)), dim3(256), 0, stream>>>(wu, wuq, s_u, ng, (int)GH, (int)I);
    ng = H * I / 128;
    qdq8<<<dim3((unsigned)((ng + 7) / 8)), dim3(256), 0, stream>>>(wd, wdq, s_d, ng, (int)GI, (int)H);
  }

  // 2) fused gate/up int8 GEMM + SwiGLU + hidden quant -> hq, s_h
  {
    const int NBN = (int)GI;                       // 86
    const int grid = (int)(M / 128) * NBN;         // 2752 (%8==0)
    gemm_gu_i8<<<dim3(grid), dim3(512), GU_LDS, stream>>>(
        xq, wgq, wuq, s_x, s_g, s_u, hq, s_h, (int)M, (int)I, (int)H, NBN);
  }
  // 3) down int8 GEMM -> fp32 out
  {
    const int NBN = (int)GH;                       // 32
    const int grid = (int)(M / 256) * NBN;         // 512 (%8==0)
    gemm_dn_i8<<<dim3(grid), dim3(512), DN_LDS, stream>>>(
        hq, wdq, s_h, s_d, out, (int)M, (int)H, (int)I, NBN);
  }
}

// Round 16
// 1171.288 us; speedup vs baseline: 1.7276x; 1.7276x over previous
//
#include <hip/hip_runtime.h>
#include <math.h>

typedef int i32x4 __attribute__((ext_vector_type(4)));
typedef float f32x4 __attribute__((ext_vector_type(4)));
typedef float f32x2 __attribute__((ext_vector_type(2)));

#define QMAXF 127.0f
#define EPSQ 1e-8f

__device__ __forceinline__ void gl_lds16(const void* g, void* l) {
  __builtin_amdgcn_global_load_lds(
      (const __attribute__((address_space(1))) unsigned int*)g,
      (__attribute__((address_space(3))) unsigned int*)l, 16, 0, 0);
}
__device__ __forceinline__ void gl_lds4(const void* g, void* l) {
  __builtin_amdgcn_global_load_lds(
      (const __attribute__((address_space(1))) unsigned int*)g,
      (__attribute__((address_space(3))) unsigned int*)l, 4, 0, 0);
}

// Group-of-128 symmetric int8 quant: fp32 in -> int8 q + transposed scales.
// Exact reference math in fp32; f32x4 loads, group per 32-lane half-wave.
__global__ __launch_bounds__(256)
void qdq8(const float* __restrict__ in, char* __restrict__ q,
          float* __restrict__ sT, long n_groups, int gpr, int R) {
  long grp = (long)blockIdx.x * 8 + (threadIdx.x >> 5);
  if (grp >= n_groups) return;
  int hl = threadIdx.x & 31;
  long base = grp * 128 + hl * 4;
  f32x4 v = *(const f32x4*)(in + base);
  float m = fmaxf(fmaxf(fabsf(v.x), fabsf(v.y)), fmaxf(fabsf(v.z), fabsf(v.w)));
#pragma unroll
  for (int off = 16; off; off >>= 1) m = fmaxf(m, __shfl_xor(m, off));
  float s = fmaxf(m / QMAXF, EPSQ);
  int q0 = (int)fminf(fmaxf(rintf(v.x / s), -QMAXF), QMAXF);
  int q1 = (int)fminf(fmaxf(rintf(v.y / s), -QMAXF), QMAXF);
  int q2 = (int)fminf(fmaxf(rintf(v.z / s), -QMAXF), QMAXF);
  int q3 = (int)fminf(fmaxf(rintf(v.w / s), -QMAXF), QMAXF);
  *(int*)(q + base) = (q0 & 0xff) | ((q1 & 0xff) << 8) |
                      ((q2 & 0xff) << 16) | ((q3 & 0xff) << 24);
  if (hl == 0) {
    long row = grp / gpr;
    long gc = grp - row * gpr;
    sT[gc * (long)R + row] = s;
  }
}

// ---------------------------------------------------------------------------
// v16: THREE dn-shaped kernels (the measured-most-efficient shape: 256x128
// tile, BK=128, 512 thr / 8 waves of 64x64 single-dtype, LDS double-buffer,
// depth-1 pipelined rescale, G4 XOR swizzle both sides).
//   EPI=0: C = acc (gate GEMM, and down GEMM)
//   EPI=1: h = silu(Gate[idx]) * acc; per-row 128-col-group quant -> Hq,sHT
// Rationale: fused 3-tensor gu ran at 1.09 POPS vs dn's 1.4 POPS with the
// same skeleton -- the 3rd staged tensor + dual accumulator is the drag.
// Gate buffer round-trip costs ~57us HBM, repaid by dn-class efficiency.
// ---------------------------------------------------------------------------

// LDS map: buf b at b*49152: A@0 (32K), B@32768 (16K).
// scales @98304 + b*1536: sSa(1024) sSb@+1024(512).
// EPI=1 extras: rmx@101376 ([2][256] f32), rs@103424 (1024). Total 104448.
#define DN_SC 98304
#define DN_RMX 101376
#define DN_RS 103424
#define DN_LDS 104448

template<int EPI>
__global__ __launch_bounds__(512, 2)
void gemm_i8(const char* __restrict__ Aq, const char* __restrict__ Bq,
             const float* __restrict__ sAT, const float* __restrict__ sBT,
             float* __restrict__ C, const float* __restrict__ Gate,
             char* __restrict__ Hq, float* __restrict__ sHT,
             int M, int N, int K, int NBN) {
  extern __shared__ __align__(16) char smem[];
  const int tid = threadIdx.x;
  const int lane = tid & 63;
  const int wid = tid >> 6;
  const int wm = wid >> 1, wn = wid & 1;
  const int wr = wm * 64, wc = wn * 64;
  const int l15 = lane & 15, l16 = lane >> 4;

  const int nwg = gridDim.x;
  const int wg = ((int)blockIdx.x & 7) * (nwg >> 3) + ((int)blockIdx.x >> 3);
  const long m0 = (long)(wg / NBN) * 256;
  const long n0 = (long)(wg % NBN) * 128;

  const long rowS = tid >> 3;
  const int offS = ((tid & 7) * 16) ^ ((int)(rowS & 7) << 4);
  const long kstr = 64L * K;
  const char* gA0 = Aq + (m0 + rowS) * K + offS;
  const char* gB0 = Bq + (n0 + rowS) * K + offS;

  const int rdSwz = (l15 & 7) << 4;
  const int colK0 = (l16 * 16) ^ rdSwz;
  const int colK1 = (64 + l16 * 16) ^ rdSwz;

  f32x4 acc[4][4];
#pragma unroll
  for (int i = 0; i < 4; i++)
#pragma unroll
    for (int j = 0; j < 4; j++) acc[i][j] = (f32x4){0.f, 0.f, 0.f, 0.f};
  const i32x4 iz = {0, 0, 0, 0};
  const int KG = K >> 7;

#define DN_STAGE(gg, bb)                                                      \
  {                                                                           \
    const long kb = (long)(gg) << 7;                                          \
    char* tb = smem + (bb) * 49152;                                           \
    _Pragma("unroll") for (int k = 0; k < 4; k++)                             \
        gl_lds16(gA0 + kb + k * kstr, tb + (tid + 512 * k) * 16);             \
    _Pragma("unroll") for (int k = 0; k < 2; k++)                             \
        gl_lds16(gB0 + kb + k * kstr, tb + 32768 + (tid + 512 * k) * 16);     \
    char* sc = smem + DN_SC + (bb) * 1536;                                    \
    if (wid < 4) {                                                            \
      gl_lds4(sAT + (long)(gg) * M + m0 + tid, sc + wid * 256);               \
    } else if (wid < 6) {                                                     \
      gl_lds4(sBT + (long)(gg) * N + n0 + (tid - 256), sc + 1024 + (wid - 4) * 256); \
    }                                                                         \
  }

  DN_STAGE(0, 0);
  __syncthreads();

  for (int g = 0; g < KG; ++g) {
    const int cb = g & 1;
    if (g + 1 < KG) DN_STAGE(g + 1, cb ^ 1);

    const char* tb = smem + cb * 49152;
    const float* sc = (const float*)(smem + DN_SC + cb * 1536);

    i32x4 af[4][2];
#pragma unroll
    for (int i = 0; i < 4; i++) {
      const int rb = (wr + i * 16 + l15) * 128;
      af[i][0] = *(const i32x4*)(tb + rb + colK0);
      af[i][1] = *(const i32x4*)(tb + rb + colK1);
    }
    f32x4 sa4[4];
#pragma unroll
    for (int i = 0; i < 4; i++)
      sa4[i] = *(const f32x4*)(sc + wr + i * 16 + l16 * 4);

    i32x4 tP;
    f32x4 msP;
#pragma unroll
    for (int j = 0; j < 4; j++) {
      const int rbB = (wc + j * 16 + l15) * 128;
      i32x4 bf0 = *(const i32x4*)(tb + 32768 + rbB + colK0);
      i32x4 bf1 = *(const i32x4*)(tb + 32768 + rbB + colK1);
      float sb = sc[256 + wc + j * 16 + l15];
#pragma unroll
      for (int i = 0; i < 4; i++) {
        i32x4 t = __builtin_amdgcn_mfma_i32_16x16x64_i8(af[i][0], bf0, iz, 0, 0, 0);
        t = __builtin_amdgcn_mfma_i32_16x16x64_i8(af[i][1], bf1, t, 0, 0, 0);
        if (j > 0 || i > 0) {
          const int pf = j * 4 + i - 1;
          const int ip = pf & 3, jp = pf >> 2;
          acc[ip][jp] += msP * __builtin_convertvector(tP, f32x4);
        }
        tP = t;
        msP = sa4[i] * sb;
      }
    }
    acc[3][3] += msP * __builtin_convertvector(tP, f32x4);
    __syncthreads();
  }

  if (EPI == 0) {
#pragma unroll
    for (int i = 0; i < 4; i++)
#pragma unroll
      for (int j = 0; j < 4; j++)
#pragma unroll
        for (int r = 0; r < 4; r++) {
          long row = m0 + wr + i * 16 + l16 * 4 + r;
          long col = n0 + wc + j * 16 + l15;
          C[row * N + col] = acc[i][j][r];
        }
  } else {
    // ---- h = silu(gate)*up; per-row (128-col group) max -> s; quantize.
    float* rmx = (float*)(smem + DN_RMX);  // [2][256]
    float* rs = (float*)(smem + DN_RS);    // [256]
    float pm[4][4];
#pragma unroll
    for (int i = 0; i < 4; i++)
#pragma unroll
      for (int r = 0; r < 4; r++) pm[i][r] = 0.f;
#pragma unroll
    for (int i = 0; i < 4; i++)
#pragma unroll
      for (int j = 0; j < 4; j++)
#pragma unroll
        for (int r = 0; r < 4; r++) {
          long row = m0 + wr + i * 16 + l16 * 4 + r;
          long col = n0 + wc + j * 16 + l15;
          float gv = Gate[row * N + col];
          float h = gv / (1.f + expf(-gv)) * acc[i][j][r];
          acc[i][j][r] = h;
          pm[i][r] = fmaxf(pm[i][r], fabsf(h));
        }
#pragma unroll
    for (int i = 0; i < 4; i++)
#pragma unroll
      for (int r = 0; r < 4; r++) {
        pm[i][r] = fmaxf(pm[i][r], __shfl_xor(pm[i][r], 1));
        pm[i][r] = fmaxf(pm[i][r], __shfl_xor(pm[i][r], 2));
        pm[i][r] = fmaxf(pm[i][r], __shfl_xor(pm[i][r], 4));
        pm[i][r] = fmaxf(pm[i][r], __shfl_xor(pm[i][r], 8));
      }
#pragma unroll
    for (int i = 0; i < 4; i++)
#pragma unroll
      for (int r = 0; r < 4; r++)
        if (l15 == i * 4 + r) rmx[wn * 256 + wr + i * 16 + l16 * 4 + r] = pm[i][r];
    __syncthreads();
    if (tid < 256) {
      float mx = fmaxf(rmx[tid], rmx[256 + tid]);
      float s = fmaxf(mx / QMAXF, EPSQ);
      rs[tid] = s;
      sHT[(n0 >> 7) * (long)M + m0 + tid] = s;
    }
    __syncthreads();
    char* sQ = smem;  // 256 rows x 128 B (buf0 dead)
#pragma unroll
    for (int i = 0; i < 4; i++) {
      f32x4 sr = *(const f32x4*)(rs + wr + i * 16 + l16 * 4);
#pragma unroll
      for (int j = 0; j < 4; j++)
#pragma unroll
        for (int r = 0; r < 4; r++) {
          float qv = fminf(fmaxf(rintf(acc[i][j][r] / sr[r]), -QMAXF), QMAXF);
          sQ[(wr + i * 16 + l16 * 4 + r) * 128 + wc + j * 16 + l15] = (char)(int)qv;
        }
    }
    __syncthreads();
    {
      int row = tid >> 1, seg = tid & 1;
      const i32x4* src = (const i32x4*)(sQ + row * 128 + seg * 64);
      i32x4* dst = (i32x4*)(Hq + (m0 + row) * N + n0 + seg * 64);
#pragma unroll
      for (int k = 0; k < 4; k++) dst[k] = src[k];
    }
  }
}

extern "C" void kernel_launch(void* const* d_in, const int* in_sizes, int n_in,
                              void* d_out, int out_size, void* d_ws, size_t ws_size,
                              hipStream_t stream) {
  (void)n_in; (void)out_size;
  const float* x  = (const float*)d_in[0];
  const float* wg = (const float*)d_in[1];
  const float* wu = (const float*)d_in[2];
  const float* wd = (const float*)d_in[3];
  float* out = (float*)d_out;

  const long H = 4096;
  const long M = in_sizes[0] / H;   // 4096 (B*S)
  const long I = in_sizes[1] / H;   // 11008
  const long GH = H >> 7;           // 32
  const long GI = I >> 7;           // 86

  char* ws = (char*)d_ws;
  size_t off = 0;
  char* xq  = ws + off; off += (size_t)(M * H);
  char* wgq = ws + off; off += (size_t)(I * H);
  char* wuq = ws + off; off += (size_t)(I * H);
  char* wdq = ws + off; off += (size_t)(H * I);
  char* hq  = ws + off; off += (size_t)(M * I);
  float* s_x = (float*)(ws + off); off += (size_t)(GH * M) * 4;
  float* s_g = (float*)(ws + off); off += (size_t)(GH * I) * 4;
  float* s_u = (float*)(ws + off); off += (size_t)(GH * I) * 4;
  float* s_d = (float*)(ws + off); off += (size_t)(GI * H) * 4;
  float* s_h = (float*)(ws + off); off += (size_t)(GI * M) * 4;
  float* gate = (float*)(ws + off); off += (size_t)(M * I) * 4;  // 180 MB
  if (ws_size < off) return;

  auto kEpi0 = gemm_i8<0>;
  auto kEpi1 = gemm_i8<1>;
  hipFuncSetAttribute((const void*)kEpi0,
                      hipFuncAttributeMaxDynamicSharedMemorySize, DN_LDS);
  hipFuncSetAttribute((const void*)kEpi1,
                      hipFuncAttributeMaxDynamicSharedMemorySize, DN_LDS);

  // 1) int8 group-quant of inputs/weights (q + transposed scales)
  {
    long ng;
    ng = M * H / 128;
    qdq8<<<dim3((unsigned)((ng + 7) / 8)), dim3(256), 0, stream>>>(x, xq, s_x, ng, (int)GH, (int)M);
    ng = I * H / 128;
    qdq8<<<dim3((unsigned)((ng + 7) / 8)), dim3(256), 0, stream>>>(wg, wgq, s_g, ng, (int)GH, (int)I);
    qdq8<<<dim3((unsigned)((ng + 7) / 8)), dim3(256), 0, stream>>>(wu, wuq, s_u, ng, (int)GH, (int)I);
    ng = H * I / 128;
    qdq8<<<dim3((unsigned)((ng + 7) / 8)), dim3(256), 0, stream>>>(wd, wdq, s_d, ng, (int)GI, (int)H);
  }

  // 2) gate = xq . wgq^T  (fp32)
  {
    const int NBN = (int)GI;                       // 86
    const int grid = (int)(M / 256) * NBN;         // 1376 (%8==0)
    kEpi0<<<dim3(grid), dim3(512), DN_LDS, stream>>>(
        xq, wgq, s_x, s_g, gate, nullptr, nullptr, nullptr,
        (int)M, (int)I, (int)H, NBN);
    // 3) h = silu(gate) * (xq . wuq^T), fused quant -> hq, s_h
    kEpi1<<<dim3(grid), dim3(512), DN_LDS, stream>>>(
        xq, wuq, s_x, s_u, nullptr, gate, hq, s_h,
        (int)M, (int)I, (int)H, NBN);
  }
  // 4) out = hq . wdq^T
  {
    const int NBN = (int)GH;                       // 32
    const int grid = (int)(M / 256) * NBN;         // 512 (%8==0)
    kEpi0<<<dim3(grid), dim3(512), DN_LDS, stream>>>(
        hq, wdq, s_h, s_d, out, nullptr, nullptr, nullptr,
        (int)M, (int)H, (int)I, NBN);
  }
}

// Round 17
// 1067.908 us; speedup vs baseline: 1.8949x; 1.0968x over previous
//
#include <hip/hip_runtime.h>
#include <math.h>

typedef int i32x4 __attribute__((ext_vector_type(4)));
typedef float f32x4 __attribute__((ext_vector_type(4)));
typedef float f32x2 __attribute__((ext_vector_type(2)));

#define QMAXF 127.0f
#define EPSQ 1e-8f

__device__ __forceinline__ void gl_lds16(const void* g, void* l) {
  __builtin_amdgcn_global_load_lds(
      (const __attribute__((address_space(1))) unsigned int*)g,
      (__attribute__((address_space(3))) unsigned int*)l, 16, 0, 0);
}
__device__ __forceinline__ void gl_lds4(const void* g, void* l) {
  __builtin_amdgcn_global_load_lds(
      (const __attribute__((address_space(1))) unsigned int*)g,
      (__attribute__((address_space(3))) unsigned int*)l, 4, 0, 0);
}

// Group-of-128 symmetric int8 quant for ALL FOUR tensors in one launch.
// Exact reference math in fp32 (max/127, maximum(.,eps), divide, rint, clip).
// f32x4 loads (16B/lane), one group per 32-lane half-wave, packed i32 store.
// Tensor select is uniform within each 32-lane group (branch at boundaries
// only) -- merging saves 3 launch gaps + tail waves on a BW-bound stage.
__global__ __launch_bounds__(256)
void qdq8_all(const float* __restrict__ x, const float* __restrict__ wg,
              const float* __restrict__ wu, const float* __restrict__ wd,
              char* __restrict__ xq, char* __restrict__ wgq,
              char* __restrict__ wuq, char* __restrict__ wdq,
              float* __restrict__ s_x, float* __restrict__ s_g,
              float* __restrict__ s_u, float* __restrict__ s_d,
              long B1, long B2, long B3, long Btot,
              int GH, int GI, int M, int I, int H) {
  long grp = (long)blockIdx.x * 8 + (threadIdx.x >> 5);
  if (grp >= Btot) return;
  int hl = threadIdx.x & 31;

  const float* in;
  char* q;
  float* sT;
  int gpr, R;
  long lg;
  if (grp < B1)      { in = x;  q = xq;  sT = s_x; gpr = GH; R = M; lg = grp; }
  else if (grp < B2) { in = wg; q = wgq; sT = s_g; gpr = GH; R = I; lg = grp - B1; }
  else if (grp < B3) { in = wu; q = wuq; sT = s_u; gpr = GH; R = I; lg = grp - B2; }
  else               { in = wd; q = wdq; sT = s_d; gpr = GI; R = H; lg = grp - B3; }

  long base = lg * 128 + hl * 4;
  f32x4 v = *(const f32x4*)(in + base);
  float m = fmaxf(fmaxf(fabsf(v.x), fabsf(v.y)), fmaxf(fabsf(v.z), fabsf(v.w)));
#pragma unroll
  for (int off = 16; off; off >>= 1) m = fmaxf(m, __shfl_xor(m, off));
  float s = fmaxf(m / QMAXF, EPSQ);
  int q0 = (int)fminf(fmaxf(rintf(v.x / s), -QMAXF), QMAXF);
  int q1 = (int)fminf(fmaxf(rintf(v.y / s), -QMAXF), QMAXF);
  int q2 = (int)fminf(fmaxf(rintf(v.z / s), -QMAXF), QMAXF);
  int q3 = (int)fminf(fmaxf(rintf(v.w / s), -QMAXF), QMAXF);
  *(int*)(q + base) = (q0 & 0xff) | ((q1 & 0xff) << 8) |
                      ((q2 & 0xff) << 16) | ((q3 & 0xff) << 24);
  if (hl == 0) {
    long row = lg / gpr;
    long gc = lg - row * gpr;
    sT[gc * (long)R + row] = s;
  }
}

// ---------------------------------------------------------------------------
// r14 skeleton (best measured, locked): 256x128 tile, BK=128 (= one quant
// group), 512 thr / 8 waves, LDS double-buffer (stage(g+1) before
// compute(g)), G4 XOR swizzle both sides, exact int32 MFMA + fp32 rescale,
// depth-1 software pipeline at the (i,j) step (MFMAs of step s overlap the
// rescale of step s-1; fully unrolled so prev indices are compile-time).
// ---------------------------------------------------------------------------

// gu LDS map (bytes): buf b at b*65536: A@0 (32K), BG@32768 (16K), BU@49152.
// scales @131072 + b*2048: sSa(1024) sSg@+1024(512) sSu@+1536(512).
// rmx@135168 (2048), rs@137216 (1024). Total 138240.
#define GU_SC 131072
#define GU_RMX 135168
#define GU_RS 137216
#define GU_LDS 138240

// Fused gate/up GEMM + SwiGLU + hidden group-quant (group = tile's 128 cols).
__global__ __launch_bounds__(512, 2)
void gemm_gu_i8(const char* __restrict__ Aq, const char* __restrict__ Bg,
                const char* __restrict__ Bu,
                const float* __restrict__ sAT, const float* __restrict__ sGT,
                const float* __restrict__ sUT,
                char* __restrict__ Hq, float* __restrict__ sHT,
                int M, int N, int K, int NBN) {
  extern __shared__ __align__(16) char smem[];
  const int tid = threadIdx.x;
  const int lane = tid & 63;
  const int wid = tid >> 6;
  const int wm = wid >> 1, wn = wid & 1;
  const int wr = wm * 64, wc = wn * 64;
  const int l15 = lane & 15, l16 = lane >> 4;

  const int nwg = gridDim.x;
  const int wg = ((int)blockIdx.x & 7) * (nwg >> 3) + ((int)blockIdx.x >> 3);
  const long m0 = (long)(wg / NBN) * 256;
  const long n0 = (long)(wg % NBN) * 128;

  const long rowS = tid >> 3;
  const int offS = ((tid & 7) * 16) ^ ((int)(rowS & 7) << 4);
  const long kstr = 64L * K;
  const char* gA0 = Aq + (m0 + rowS) * K + offS;   // k = 0..3
  const char* gG0 = Bg + (n0 + rowS) * K + offS;   // k = 0..1
  const char* gU0 = Bu + (n0 + rowS) * K + offS;

  const int rdSwz = (l15 & 7) << 4;
  const int colK0 = (l16 * 16) ^ rdSwz;
  const int colK1 = (64 + l16 * 16) ^ rdSwz;

  f32x4 accg[4][4], accu[4][4];
#pragma unroll
  for (int i = 0; i < 4; i++)
#pragma unroll
    for (int j = 0; j < 4; j++) {
      accg[i][j] = (f32x4){0.f, 0.f, 0.f, 0.f};
      accu[i][j] = (f32x4){0.f, 0.f, 0.f, 0.f};
    }
  const i32x4 iz = {0, 0, 0, 0};
  const int KG = K >> 7;

#define GU_STAGE(gg, bb)                                                      \
  {                                                                           \
    const long kb = (long)(gg) << 7;                                          \
    char* tb = smem + (bb) * 65536;                                           \
    _Pragma("unroll") for (int k = 0; k < 4; k++)                             \
        gl_lds16(gA0 + kb + k * kstr, tb + (tid + 512 * k) * 16);             \
    _Pragma("unroll") for (int k = 0; k < 2; k++) {                           \
      gl_lds16(gG0 + kb + k * kstr, tb + 32768 + (tid + 512 * k) * 16);       \
      gl_lds16(gU0 + kb + k * kstr, tb + 49152 + (tid + 512 * k) * 16);       \
    }                                                                         \
    char* sc = smem + GU_SC + (bb) * 2048;                                    \
    if (wid < 4) {                                                            \
      gl_lds4(sAT + (long)(gg) * M + m0 + tid, sc + wid * 256);               \
    } else if (wid < 6) {                                                     \
      gl_lds4(sGT + (long)(gg) * N + n0 + (tid - 256), sc + 1024 + (wid - 4) * 256); \
    } else {                                                                  \
      gl_lds4(sUT + (long)(gg) * N + n0 + (tid - 384), sc + 1536 + (wid - 6) * 256); \
    }                                                                         \
  }

  GU_STAGE(0, 0);
  __syncthreads();

  for (int g = 0; g < KG; ++g) {
    const int cb = g & 1;
    if (g + 1 < KG) GU_STAGE(g + 1, cb ^ 1);

    const char* tb = smem + cb * 65536;
    const float* sc = (const float*)(smem + GU_SC + cb * 2048);

    i32x4 af[4][2];
#pragma unroll
    for (int i = 0; i < 4; i++) {
      const int rb = (wr + i * 16 + l15) * 128;
      af[i][0] = *(const i32x4*)(tb + rb + colK0);
      af[i][1] = *(const i32x4*)(tb + rb + colK1);
    }
    f32x4 sa4[4];
#pragma unroll
    for (int i = 0; i < 4; i++)
      sa4[i] = *(const f32x4*)(sc + wr + i * 16 + l16 * 4);

    // depth-1 pipelined (j,i) loop: MFMAs of step s overlap rescale of s-1
    i32x4 tgP, tuP;
    f32x4 mgP, muP;
#pragma unroll
    for (int j = 0; j < 4; j++) {
      const int rbB = (wc + j * 16 + l15) * 128;
      i32x4 bgf0 = *(const i32x4*)(tb + 32768 + rbB + colK0);
      i32x4 bgf1 = *(const i32x4*)(tb + 32768 + rbB + colK1);
      i32x4 buf0 = *(const i32x4*)(tb + 49152 + rbB + colK0);
      i32x4 buf1 = *(const i32x4*)(tb + 49152 + rbB + colK1);
      float sbg = sc[256 + wc + j * 16 + l15];
      float sbu = sc[384 + wc + j * 16 + l15];
#pragma unroll
      for (int i = 0; i < 4; i++) {
        i32x4 tg = __builtin_amdgcn_mfma_i32_16x16x64_i8(af[i][0], bgf0, iz, 0, 0, 0);
        tg = __builtin_amdgcn_mfma_i32_16x16x64_i8(af[i][1], bgf1, tg, 0, 0, 0);
        i32x4 tu = __builtin_amdgcn_mfma_i32_16x16x64_i8(af[i][0], buf0, iz, 0, 0, 0);
        tu = __builtin_amdgcn_mfma_i32_16x16x64_i8(af[i][1], buf1, tu, 0, 0, 0);
        if (j > 0 || i > 0) {
          const int pf = j * 4 + i - 1;
          const int ip = pf & 3, jp = pf >> 2;
          accg[ip][jp] += mgP * __builtin_convertvector(tgP, f32x4);
          accu[ip][jp] += muP * __builtin_convertvector(tuP, f32x4);
        }
        tgP = tg; tuP = tu;
        mgP = sa4[i] * sbg; muP = sa4[i] * sbu;
      }
    }
    accg[3][3] += mgP * __builtin_convertvector(tgP, f32x4);
    accu[3][3] += muP * __builtin_convertvector(tuP, f32x4);
    __syncthreads();  // drains vmcnt: stage(g+1) resident; all reads of cb done
  }

  // ---- epilogue: h = silu(g)*u; per-row (128-col group) max -> s; quantize.
  float* rmx = (float*)(smem + GU_RMX);  // [2][256]
  float* rs = (float*)(smem + GU_RS);    // [256]
  float pm[4][4];
#pragma unroll
  for (int i = 0; i < 4; i++)
#pragma unroll
    for (int r = 0; r < 4; r++) pm[i][r] = 0.f;
#pragma unroll
  for (int i = 0; i < 4; i++)
#pragma unroll
    for (int j = 0; j < 4; j++)
#pragma unroll
      for (int r = 0; r < 4; r++) {
        float gv = accg[i][j][r];
        float h = gv / (1.f + expf(-gv)) * accu[i][j][r];
        accu[i][j][r] = h;
        pm[i][r] = fmaxf(pm[i][r], fabsf(h));
      }
#pragma unroll
  for (int i = 0; i < 4; i++)
#pragma unroll
    for (int r = 0; r < 4; r++) {
      pm[i][r] = fmaxf(pm[i][r], __shfl_xor(pm[i][r], 1));
      pm[i][r] = fmaxf(pm[i][r], __shfl_xor(pm[i][r], 2));
      pm[i][r] = fmaxf(pm[i][r], __shfl_xor(pm[i][r], 4));
      pm[i][r] = fmaxf(pm[i][r], __shfl_xor(pm[i][r], 8));
    }
#pragma unroll
  for (int i = 0; i < 4; i++)
#pragma unroll
    for (int r = 0; r < 4; r++)
      if (l15 == i * 4 + r) rmx[wn * 256 + wr + i * 16 + l16 * 4 + r] = pm[i][r];
  __syncthreads();
  if (tid < 256) {
    float mx = fmaxf(rmx[tid], rmx[256 + tid]);
    float s = fmaxf(mx / QMAXF, EPSQ);
    rs[tid] = s;
    sHT[(n0 >> 7) * (long)M + m0 + tid] = s;
  }
  __syncthreads();
  char* sQ = smem;  // 256 rows x 128 B
#pragma unroll
  for (int i = 0; i < 4; i++) {
    f32x4 sr = *(const f32x4*)(rs + wr + i * 16 + l16 * 4);
#pragma unroll
    for (int j = 0; j < 4; j++)
#pragma unroll
      for (int r = 0; r < 4; r++) {
        float qv = fminf(fmaxf(rintf(accu[i][j][r] / sr[r]), -QMAXF), QMAXF);
        sQ[(wr + i * 16 + l16 * 4 + r) * 128 + wc + j * 16 + l15] = (char)(int)qv;
      }
  }
  __syncthreads();
  {
    int row = tid >> 1, seg = tid & 1;
    const i32x4* src = (const i32x4*)(sQ + row * 128 + seg * 64);
    i32x4* dst = (i32x4*)(Hq + (m0 + row) * N + n0 + seg * 64);
#pragma unroll
    for (int k = 0; k < 4; k++) dst[k] = src[k];
  }
}

// dn LDS map: buf b at b*49152: A@0 (32K), B@32768 (16K).
// scales @98304 + b*1536: sSa(1024) sSb@+1024(512). Total 101376.
#define DN_SC 98304
#define DN_LDS 101376

// Down GEMM: fp32 out = dequant(A_i8) . dequant(B_i8)^T with exact int cores.
__global__ __launch_bounds__(512, 2)
void gemm_dn_i8(const char* __restrict__ Aq, const char* __restrict__ Bq,
                const float* __restrict__ sAT, const float* __restrict__ sBT,
                float* __restrict__ C, int M, int N, int K, int NBN) {
  extern __shared__ __align__(16) char smem[];
  const int tid = threadIdx.x;
  const int lane = tid & 63;
  const int wid = tid >> 6;
  const int wm = wid >> 1, wn = wid & 1;
  const int wr = wm * 64, wc = wn * 64;
  const int l15 = lane & 15, l16 = lane >> 4;

  const int nwg = gridDim.x;
  const int wg = ((int)blockIdx.x & 7) * (nwg >> 3) + ((int)blockIdx.x >> 3);
  const long m0 = (long)(wg / NBN) * 256;
  const long n0 = (long)(wg % NBN) * 128;

  const long rowS = tid >> 3;
  const int offS = ((tid & 7) * 16) ^ ((int)(rowS & 7) << 4);
  const long kstr = 64L * K;
  const char* gA0 = Aq + (m0 + rowS) * K + offS;
  const char* gB0 = Bq + (n0 + rowS) * K + offS;

  const int rdSwz = (l15 & 7) << 4;
  const int colK0 = (l16 * 16) ^ rdSwz;
  const int colK1 = (64 + l16 * 16) ^ rdSwz;

  f32x4 acc[4][4];
#pragma unroll
  for (int i = 0; i < 4; i++)
#pragma unroll
    for (int j = 0; j < 4; j++) acc[i][j] = (f32x4){0.f, 0.f, 0.f, 0.f};
  const i32x4 iz = {0, 0, 0, 0};
  const int KG = K >> 7;

#define DN_STAGE(gg, bb)                                                      \
  {                                                                           \
    const long kb = (long)(gg) << 7;                                          \
    char* tb = smem + (bb) * 49152;                                           \
    _Pragma("unroll") for (int k = 0; k < 4; k++)                             \
        gl_lds16(gA0 + kb + k * kstr, tb + (tid + 512 * k) * 16);             \
    _Pragma("unroll") for (int k = 0; k < 2; k++)                             \
        gl_lds16(gB0 + kb + k * kstr, tb + 32768 + (tid + 512 * k) * 16);     \
    char* sc = smem + DN_SC + (bb) * 1536;                                    \
    if (wid < 4) {                                                            \
      gl_lds4(sAT + (long)(gg) * M + m0 + tid, sc + wid * 256);               \
    } else if (wid < 6) {                                                     \
      gl_lds4(sBT + (long)(gg) * N + n0 + (tid - 256), sc + 1024 + (wid - 4) * 256); \
    }                                                                         \
  }

  DN_STAGE(0, 0);
  __syncthreads();

  for (int g = 0; g < KG; ++g) {
    const int cb = g & 1;
    if (g + 1 < KG) DN_STAGE(g + 1, cb ^ 1);

    const char* tb = smem + cb * 49152;
    const float* sc = (const float*)(smem + DN_SC + cb * 1536);

    i32x4 af[4][2];
#pragma unroll
    for (int i = 0; i < 4; i++) {
      const int rb = (wr + i * 16 + l15) * 128;
      af[i][0] = *(const i32x4*)(tb + rb + colK0);
      af[i][1] = *(const i32x4*)(tb + rb + colK1);
    }
    f32x4 sa4[4];
#pragma unroll
    for (int i = 0; i < 4; i++)
      sa4[i] = *(const f32x4*)(sc + wr + i * 16 + l16 * 4);

    i32x4 tP;
    f32x4 msP;
#pragma unroll
    for (int j = 0; j < 4; j++) {
      const int rbB = (wc + j * 16 + l15) * 128;
      i32x4 bf0 = *(const i32x4*)(tb + 32768 + rbB + colK0);
      i32x4 bf1 = *(const i32x4*)(tb + 32768 + rbB + colK1);
      float sb = sc[256 + wc + j * 16 + l15];
#pragma unroll
      for (int i = 0; i < 4; i++) {
        i32x4 t = __builtin_amdgcn_mfma_i32_16x16x64_i8(af[i][0], bf0, iz, 0, 0, 0);
        t = __builtin_amdgcn_mfma_i32_16x16x64_i8(af[i][1], bf1, t, 0, 0, 0);
        if (j > 0 || i > 0) {
          const int pf = j * 4 + i - 1;
          const int ip = pf & 3, jp = pf >> 2;
          acc[ip][jp] += msP * __builtin_convertvector(tP, f32x4);
        }
        tP = t;
        msP = sa4[i] * sb;
      }
    }
    acc[3][3] += msP * __builtin_convertvector(tP, f32x4);
    __syncthreads();
  }

#pragma unroll
  for (int i = 0; i < 4; i++)
#pragma unroll
    for (int j = 0; j < 4; j++)
#pragma unroll
      for (int r = 0; r < 4; r++) {
        long row = m0 + wr + i * 16 + l16 * 4 + r;
        long col = n0 + wc + j * 16 + l15;
        C[row * N + col] = acc[i][j][r];
      }
}

extern "C" void kernel_launch(void* const* d_in, const int* in_sizes, int n_in,
                              void* d_out, int out_size, void* d_ws, size_t ws_size,
                              hipStream_t stream) {
  (void)n_in; (void)out_size;
  const float* x  = (const float*)d_in[0];
  const float* wg = (const float*)d_in[1];
  const float* wu = (const float*)d_in[2];
  const float* wd = (const float*)d_in[3];
  float* out = (float*)d_out;

  const long H = 4096;
  const long M = in_sizes[0] / H;   // 4096 (B*S)
  const long I = in_sizes[1] / H;   // 11008
  const long GH = H >> 7;           // 32
  const long GI = I >> 7;           // 86

  char* ws = (char*)d_ws;
  size_t off = 0;
  char* xq  = ws + off; off += (size_t)(M * H);
  char* wgq = ws + off; off += (size_t)(I * H);
  char* wuq = ws + off; off += (size_t)(I * H);
  char* wdq = ws + off; off += (size_t)(H * I);
  char* hq  = ws + off; off += (size_t)(M * I);
  float* s_x = (float*)(ws + off); off += (size_t)(GH * M) * 4;
  float* s_g = (float*)(ws + off); off += (size_t)(GH * I) * 4;
  float* s_u = (float*)(ws + off); off += (size_t)(GH * I) * 4;
  float* s_d = (float*)(ws + off); off += (size_t)(GI * H) * 4;
  float* s_h = (float*)(ws + off); off += (size_t)(GI * M) * 4;
  if (ws_size < off) return;

  hipFuncSetAttribute((const void*)gemm_gu_i8,
                      hipFuncAttributeMaxDynamicSharedMemorySize, GU_LDS);
  hipFuncSetAttribute((const void*)gemm_dn_i8,
                      hipFuncAttributeMaxDynamicSharedMemorySize, DN_LDS);

  // 1) int8 group-quant of all inputs/weights in ONE launch
  {
    const long G1 = M * H / 128;
    const long G2 = I * H / 128;
    const long B1 = G1, B2 = G1 + G2, B3 = B2 + G2;
    const long Btot = B3 + H * I / 128;
    qdq8_all<<<dim3((unsigned)((Btot + 7) / 8)), dim3(256), 0, stream>>>(
        x, wg, wu, wd, xq, wgq, wuq, wdq, s_x, s_g, s_u, s_d,
        B1, B2, B3, Btot, (int)GH, (int)GI, (int)M, (int)I, (int)H);
  }

  // 2) fused gate/up int8 GEMM + SwiGLU + hidden quant -> hq, s_h
  {
    const int NBN = (int)GI;                       // 86
    const int grid = (int)(M / 256) * NBN;         // 1376 (%8==0)
    gemm_gu_i8<<<dim3(grid), dim3(512), GU_LDS, stream>>>(
        xq, wgq, wuq, s_x, s_g, s_u, hq, s_h, (int)M, (int)I, (int)H, NBN);
  }
  // 3) down int8 GEMM -> fp32 out
  {
    const int NBN = (int)GH;                       // 32
    const int grid = (int)(M / 256) * NBN;         // 512 (%8==0)
    gemm_dn_i8<<<dim3(grid), dim3(512), DN_LDS, stream>>>(
        hq, wdq, s_h, s_d, out, (int)M, (int)H, (int)I, NBN);
  }
}

// Round 18
// 1034.475 us; speedup vs baseline: 1.9561x; 1.0323x over previous
//
#include <hip/hip_runtime.h>
#include <math.h>

typedef int i32x4 __attribute__((ext_vector_type(4)));
typedef float f32x4 __attribute__((ext_vector_type(4)));
typedef float f32x2 __attribute__((ext_vector_type(2)));

#define QMAXF 127.0f
#define EPSQ 1e-8f

__device__ __forceinline__ void gl_lds16(const void* g, void* l) {
  __builtin_amdgcn_global_load_lds(
      (const __attribute__((address_space(1))) unsigned int*)g,
      (__attribute__((address_space(3))) unsigned int*)l, 16, 0, 0);
}
__device__ __forceinline__ void gl_lds4(const void* g, void* l) {
  __builtin_amdgcn_global_load_lds(
      (const __attribute__((address_space(1))) unsigned int*)g,
      (__attribute__((address_space(3))) unsigned int*)l, 4, 0, 0);
}

// Group-of-128 symmetric int8 quant for ALL FOUR tensors in one launch.
// Exact reference math in fp32 (max/127, maximum(.,eps), divide, rint, clip).
__global__ __launch_bounds__(256)
void qdq8_all(const float* __restrict__ x, const float* __restrict__ wg,
              const float* __restrict__ wu, const float* __restrict__ wd,
              char* __restrict__ xq, char* __restrict__ wgq,
              char* __restrict__ wuq, char* __restrict__ wdq,
              float* __restrict__ s_x, float* __restrict__ s_g,
              float* __restrict__ s_u, float* __restrict__ s_d,
              long B1, long B2, long B3, long Btot,
              int GH, int GI, int M, int I, int H) {
  long grp = (long)blockIdx.x * 8 + (threadIdx.x >> 5);
  if (grp >= Btot) return;
  int hl = threadIdx.x & 31;

  const float* in;
  char* q;
  float* sT;
  int gpr, R;
  long lg;
  if (grp < B1)      { in = x;  q = xq;  sT = s_x; gpr = GH; R = M; lg = grp; }
  else if (grp < B2) { in = wg; q = wgq; sT = s_g; gpr = GH; R = I; lg = grp - B1; }
  else if (grp < B3) { in = wu; q = wuq; sT = s_u; gpr = GH; R = I; lg = grp - B2; }
  else               { in = wd; q = wdq; sT = s_d; gpr = GI; R = H; lg = grp - B3; }

  long base = lg * 128 + hl * 4;
  f32x4 v = *(const f32x4*)(in + base);
  float m = fmaxf(fmaxf(fabsf(v.x), fabsf(v.y)), fmaxf(fabsf(v.z), fabsf(v.w)));
#pragma unroll
  for (int off = 16; off; off >>= 1) m = fmaxf(m, __shfl_xor(m, off));
  float s = fmaxf(m / QMAXF, EPSQ);
  int q0 = (int)fminf(fmaxf(rintf(v.x / s), -QMAXF), QMAXF);
  int q1 = (int)fminf(fmaxf(rintf(v.y / s), -QMAXF), QMAXF);
  int q2 = (int)fminf(fmaxf(rintf(v.z / s), -QMAXF), QMAXF);
  int q3 = (int)fminf(fmaxf(rintf(v.w / s), -QMAXF), QMAXF);
  *(int*)(q + base) = (q0 & 0xff) | ((q1 & 0xff) << 8) |
                      ((q2 & 0xff) << 16) | ((q3 & 0xff) << 24);
  if (hl == 0) {
    long row = lg / gpr;
    long gc = lg - row * gpr;
    sT[gc * (long)R + row] = s;
  }
}

// ---------------------------------------------------------------------------
// r14 skeleton (best measured, locked): 256x128 tile, BK=128 (= one quant
// group), 512 thr / 8 waves, LDS double-buffer (stage(g+1) before
// compute(g)), G4 XOR swizzle both sides, exact int32 MFMA + fp32 rescale,
// depth-1 pipelined rescale.
// v18: N-MAJOR grid for gu (m0 = wg&15, n0 = wg>>4): 16 consecutive blocks
// share the B-pair (1MB, L2-hot) and A (45MB) goes L3-resident, instead of
// m-major's 86-distinct-B streaming (FETCH 756MB vs ideal 136MB). dn already
// runs one exact L2-friendly round -- untouched.
// ---------------------------------------------------------------------------

// gu LDS map (bytes): buf b at b*65536: A@0 (32K), BG@32768 (16K), BU@49152.
// scales @131072 + b*2048: sSa(1024) sSg@+1024(512) sSu@+1536(512).
// rmx@135168 (2048), rs@137216 (1024). Total 138240.
#define GU_SC 131072
#define GU_RMX 135168
#define GU_RS 137216
#define GU_LDS 138240

// Fused gate/up GEMM + SwiGLU + hidden group-quant (group = tile's 128 cols).
__global__ __launch_bounds__(512, 2)
void gemm_gu_i8(const char* __restrict__ Aq, const char* __restrict__ Bg,
                const char* __restrict__ Bu,
                const float* __restrict__ sAT, const float* __restrict__ sGT,
                const float* __restrict__ sUT,
                char* __restrict__ Hq, float* __restrict__ sHT,
                int M, int N, int K, int NBN) {
  extern __shared__ __align__(16) char smem[];
  const int tid = threadIdx.x;
  const int lane = tid & 63;
  const int wid = tid >> 6;
  const int wm = wid >> 1, wn = wid & 1;
  const int wr = wm * 64, wc = wn * 64;
  const int l15 = lane & 15, l16 = lane >> 4;

  const int nwg = gridDim.x;
  const int wg = ((int)blockIdx.x & 7) * (nwg >> 3) + ((int)blockIdx.x >> 3);
  // n-major decode: NBM = M/256 = 16; consecutive wg share the B-panels.
  const int NBM = M >> 8;
  const long m0 = (long)(wg % NBM) * 256;
  const long n0 = (long)(wg / NBM) * 128;

  const long rowS = tid >> 3;
  const int offS = ((tid & 7) * 16) ^ ((int)(rowS & 7) << 4);
  const long kstr = 64L * K;
  const char* gA0 = Aq + (m0 + rowS) * K + offS;   // k = 0..3
  const char* gG0 = Bg + (n0 + rowS) * K + offS;   // k = 0..1
  const char* gU0 = Bu + (n0 + rowS) * K + offS;

  const int rdSwz = (l15 & 7) << 4;
  const int colK0 = (l16 * 16) ^ rdSwz;
  const int colK1 = (64 + l16 * 16) ^ rdSwz;

  f32x4 accg[4][4], accu[4][4];
#pragma unroll
  for (int i = 0; i < 4; i++)
#pragma unroll
    for (int j = 0; j < 4; j++) {
      accg[i][j] = (f32x4){0.f, 0.f, 0.f, 0.f};
      accu[i][j] = (f32x4){0.f, 0.f, 0.f, 0.f};
    }
  const i32x4 iz = {0, 0, 0, 0};
  const int KG = K >> 7;

#define GU_STAGE(gg, bb)                                                      \
  {                                                                           \
    const long kb = (long)(gg) << 7;                                          \
    char* tb = smem + (bb) * 65536;                                           \
    _Pragma("unroll") for (int k = 0; k < 4; k++)                             \
        gl_lds16(gA0 + kb + k * kstr, tb + (tid + 512 * k) * 16);             \
    _Pragma("unroll") for (int k = 0; k < 2; k++) {                           \
      gl_lds16(gG0 + kb + k * kstr, tb + 32768 + (tid + 512 * k) * 16);       \
      gl_lds16(gU0 + kb + k * kstr, tb + 49152 + (tid + 512 * k) * 16);       \
    }                                                                         \
    char* sc = smem + GU_SC + (bb) * 2048;                                    \
    if (wid < 4) {                                                            \
      gl_lds4(sAT + (long)(gg) * M + m0 + tid, sc + wid * 256);               \
    } else if (wid < 6) {                                                     \
      gl_lds4(sGT + (long)(gg) * N + n0 + (tid - 256), sc + 1024 + (wid - 4) * 256); \
    } else {                                                                  \
      gl_lds4(sUT + (long)(gg) * N + n0 + (tid - 384), sc + 1536 + (wid - 6) * 256); \
    }                                                                         \
  }

  GU_STAGE(0, 0);
  __syncthreads();

  for (int g = 0; g < KG; ++g) {
    const int cb = g & 1;
    if (g + 1 < KG) GU_STAGE(g + 1, cb ^ 1);

    const char* tb = smem + cb * 65536;
    const float* sc = (const float*)(smem + GU_SC + cb * 2048);

    i32x4 af[4][2];
#pragma unroll
    for (int i = 0; i < 4; i++) {
      const int rb = (wr + i * 16 + l15) * 128;
      af[i][0] = *(const i32x4*)(tb + rb + colK0);
      af[i][1] = *(const i32x4*)(tb + rb + colK1);
    }
    f32x4 sa4[4];
#pragma unroll
    for (int i = 0; i < 4; i++)
      sa4[i] = *(const f32x4*)(sc + wr + i * 16 + l16 * 4);

    // depth-1 pipelined (j,i) loop: MFMAs of step s overlap rescale of s-1
    i32x4 tgP, tuP;
    f32x4 mgP, muP;
#pragma unroll
    for (int j = 0; j < 4; j++) {
      const int rbB = (wc + j * 16 + l15) * 128;
      i32x4 bgf0 = *(const i32x4*)(tb + 32768 + rbB + colK0);
      i32x4 bgf1 = *(const i32x4*)(tb + 32768 + rbB + colK1);
      i32x4 buf0 = *(const i32x4*)(tb + 49152 + rbB + colK0);
      i32x4 buf1 = *(const i32x4*)(tb + 49152 + rbB + colK1);
      float sbg = sc[256 + wc + j * 16 + l15];
      float sbu = sc[384 + wc + j * 16 + l15];
#pragma unroll
      for (int i = 0; i < 4; i++) {
        i32x4 tg = __builtin_amdgcn_mfma_i32_16x16x64_i8(af[i][0], bgf0, iz, 0, 0, 0);
        tg = __builtin_amdgcn_mfma_i32_16x16x64_i8(af[i][1], bgf1, tg, 0, 0, 0);
        i32x4 tu = __builtin_amdgcn_mfma_i32_16x16x64_i8(af[i][0], buf0, iz, 0, 0, 0);
        tu = __builtin_amdgcn_mfma_i32_16x16x64_i8(af[i][1], buf1, tu, 0, 0, 0);
        if (j > 0 || i > 0) {
          const int pf = j * 4 + i - 1;
          const int ip = pf & 3, jp = pf >> 2;
          accg[ip][jp] += mgP * __builtin_convertvector(tgP, f32x4);
          accu[ip][jp] += muP * __builtin_convertvector(tuP, f32x4);
        }
        tgP = tg; tuP = tu;
        mgP = sa4[i] * sbg; muP = sa4[i] * sbu;
      }
    }
    accg[3][3] += mgP * __builtin_convertvector(tgP, f32x4);
    accu[3][3] += muP * __builtin_convertvector(tuP, f32x4);
    __syncthreads();  // drains vmcnt: stage(g+1) resident; all reads of cb done
  }

  // ---- epilogue: h = silu(g)*u; per-row (128-col group) max -> s; quantize.
  float* rmx = (float*)(smem + GU_RMX);  // [2][256]
  float* rs = (float*)(smem + GU_RS);    // [256]
  float pm[4][4];
#pragma unroll
  for (int i = 0; i < 4; i++)
#pragma unroll
    for (int r = 0; r < 4; r++) pm[i][r] = 0.f;
#pragma unroll
  for (int i = 0; i < 4; i++)
#pragma unroll
    for (int j = 0; j < 4; j++)
#pragma unroll
      for (int r = 0; r < 4; r++) {
        float gv = accg[i][j][r];
        float h = gv / (1.f + expf(-gv)) * accu[i][j][r];
        accu[i][j][r] = h;
        pm[i][r] = fmaxf(pm[i][r], fabsf(h));
      }
#pragma unroll
  for (int i = 0; i < 4; i++)
#pragma unroll
    for (int r = 0; r < 4; r++) {
      pm[i][r] = fmaxf(pm[i][r], __shfl_xor(pm[i][r], 1));
      pm[i][r] = fmaxf(pm[i][r], __shfl_xor(pm[i][r], 2));
      pm[i][r] = fmaxf(pm[i][r], __shfl_xor(pm[i][r], 4));
      pm[i][r] = fmaxf(pm[i][r], __shfl_xor(pm[i][r], 8));
    }
#pragma unroll
  for (int i = 0; i < 4; i++)
#pragma unroll
    for (int r = 0; r < 4; r++)
      if (l15 == i * 4 + r) rmx[wn * 256 + wr + i * 16 + l16 * 4 + r] = pm[i][r];
  __syncthreads();
  if (tid < 256) {
    float mx = fmaxf(rmx[tid], rmx[256 + tid]);
    float s = fmaxf(mx / QMAXF, EPSQ);
    rs[tid] = s;
    sHT[(n0 >> 7) * (long)M + m0 + tid] = s;
  }
  __syncthreads();
  char* sQ = smem;  // 256 rows x 128 B
#pragma unroll
  for (int i = 0; i < 4; i++) {
    f32x4 sr = *(const f32x4*)(rs + wr + i * 16 + l16 * 4);
#pragma unroll
    for (int j = 0; j < 4; j++)
#pragma unroll
      for (int r = 0; r < 4; r++) {
        float qv = fminf(fmaxf(rintf(accu[i][j][r] / sr[r]), -QMAXF), QMAXF);
        sQ[(wr + i * 16 + l16 * 4 + r) * 128 + wc + j * 16 + l15] = (char)(int)qv;
      }
  }
  __syncthreads();
  {
    int row = tid >> 1, seg = tid & 1;
    const i32x4* src = (const i32x4*)(sQ + row * 128 + seg * 64);
    i32x4* dst = (i32x4*)(Hq + (m0 + row) * N + n0 + seg * 64);
#pragma unroll
    for (int k = 0; k < 4; k++) dst[k] = src[k];
  }
}

// dn LDS map: buf b at b*49152: A@0 (32K), B@32768 (16K).
// scales @98304 + b*1536: sSa(1024) sSb@+1024(512). Total 101376.
#define DN_SC 98304
#define DN_LDS 101376

// Down GEMM: fp32 out = dequant(A_i8) . dequant(B_i8)^T with exact int cores.
__global__ __launch_bounds__(512, 2)
void gemm_dn_i8(const char* __restrict__ Aq, const char* __restrict__ Bq,
                const float* __restrict__ sAT, const float* __restrict__ sBT,
                float* __restrict__ C, int M, int N, int K, int NBN) {
  extern __shared__ __align__(16) char smem[];
  const int tid = threadIdx.x;
  const int lane = tid & 63;
  const int wid = tid >> 6;
  const int wm = wid >> 1, wn = wid & 1;
  const int wr = wm * 64, wc = wn * 64;
  const int l15 = lane & 15, l16 = lane >> 4;

  const int nwg = gridDim.x;
  const int wg = ((int)blockIdx.x & 7) * (nwg >> 3) + ((int)blockIdx.x >> 3);
  const long m0 = (long)(wg / NBN) * 256;
  const long n0 = (long)(wg % NBN) * 128;

  const long rowS = tid >> 3;
  const int offS = ((tid & 7) * 16) ^ ((int)(rowS & 7) << 4);
  const long kstr = 64L * K;
  const char* gA0 = Aq + (m0 + rowS) * K + offS;
  const char* gB0 = Bq + (n0 + rowS) * K + offS;

  const int rdSwz = (l15 & 7) << 4;
  const int colK0 = (l16 * 16) ^ rdSwz;
  const int colK1 = (64 + l16 * 16) ^ rdSwz;

  f32x4 acc[4][4];
#pragma unroll
  for (int i = 0; i < 4; i++)
#pragma unroll
    for (int j = 0; j < 4; j++) acc[i][j] = (f32x4){0.f, 0.f, 0.f, 0.f};
  const i32x4 iz = {0, 0, 0, 0};
  const int KG = K >> 7;

#define DN_STAGE(gg, bb)                                                      \
  {                                                                           \
    const long kb = (long)(gg) << 7;                                          \
    char* tb = smem + (bb) * 49152;                                           \
    _Pragma("unroll") for (int k = 0; k < 4; k++)                             \
        gl_lds16(gA0 + kb + k * kstr, tb + (tid + 512 * k) * 16);             \
    _Pragma("unroll") for (int k = 0; k < 2; k++)                             \
        gl_lds16(gB0 + kb + k * kstr, tb + 32768 + (tid + 512 * k) * 16);     \
    char* sc = smem + DN_SC + (bb) * 1536;                                    \
    if (wid < 4) {                                                            \
      gl_lds4(sAT + (long)(gg) * M + m0 + tid, sc + wid * 256);               \
    } else if (wid < 6) {                                                     \
      gl_lds4(sBT + (long)(gg) * N + n0 + (tid - 256), sc + 1024 + (wid - 4) * 256); \
    }                                                                         \
  }

  DN_STAGE(0, 0);
  __syncthreads();

  for (int g = 0; g < KG; ++g) {
    const int cb = g & 1;
    if (g + 1 < KG) DN_STAGE(g + 1, cb ^ 1);

    const char* tb = smem + cb * 49152;
    const float* sc = (const float*)(smem + DN_SC + cb * 1536);

    i32x4 af[4][2];
#pragma unroll
    for (int i = 0; i < 4; i++) {
      const int rb = (wr + i * 16 + l15) * 128;
      af[i][0] = *(const i32x4*)(tb + rb + colK0);
      af[i][1] = *(const i32x4*)(tb + rb + colK1);
    }
    f32x4 sa4[4];
#pragma unroll
    for (int i = 0; i < 4; i++)
      sa4[i] = *(const f32x4*)(sc + wr + i * 16 + l16 * 4);

    i32x4 tP;
    f32x4 msP;
#pragma unroll
    for (int j = 0; j < 4; j++) {
      const int rbB = (wc + j * 16 + l15) * 128;
      i32x4 bf0 = *(const i32x4*)(tb + 32768 + rbB + colK0);
      i32x4 bf1 = *(const i32x4*)(tb + 32768 + rbB + colK1);
      float sb = sc[256 + wc + j * 16 + l15];
#pragma unroll
      for (int i = 0; i < 4; i++) {
        i32x4 t = __builtin_amdgcn_mfma_i32_16x16x64_i8(af[i][0], bf0, iz, 0, 0, 0);
        t = __builtin_amdgcn_mfma_i32_16x16x64_i8(af[i][1], bf1, t, 0, 0, 0);
        if (j > 0 || i > 0) {
          const int pf = j * 4 + i - 1;
          const int ip = pf & 3, jp = pf >> 2;
          acc[ip][jp] += msP * __builtin_convertvector(tP, f32x4);
        }
        tP = t;
        msP = sa4[i] * sb;
      }
    }
    acc[3][3] += msP * __builtin_convertvector(tP, f32x4);
    __syncthreads();
  }

#pragma unroll
  for (int i = 0; i < 4; i++)
#pragma unroll
    for (int j = 0; j < 4; j++)
#pragma unroll
      for (int r = 0; r < 4; r++) {
        long row = m0 + wr + i * 16 + l16 * 4 + r;
        long col = n0 + wc + j * 16 + l15;
        C[row * N + col] = acc[i][j][r];
      }
}

extern "C" void kernel_launch(void* const* d_in, const int* in_sizes, int n_in,
                              void* d_out, int out_size, void* d_ws, size_t ws_size,
                              hipStream_t stream) {
  (void)n_in; (void)out_size;
  const float* x  = (const float*)d_in[0];
  const float* wg = (const float*)d_in[1];
  const float* wu = (const float*)d_in[2];
  const float* wd = (const float*)d_in[3];
  float* out = (float*)d_out;

  const long H = 4096;
  const long M = in_sizes[0] / H;   // 4096 (B*S)
  const long I = in_sizes[1] / H;   // 11008
  const long GH = H >> 7;           // 32
  const long GI = I >> 7;           // 86

  char* ws = (char*)d_ws;
  size_t off = 0;
  char* xq  = ws + off; off += (size_t)(M * H);
  char* wgq = ws + off; off += (size_t)(I * H);
  char* wuq = ws + off; off += (size_t)(I * H);
  char* wdq = ws + off; off += (size_t)(H * I);
  char* hq  = ws + off; off += (size_t)(M * I);
  float* s_x = (float*)(ws + off); off += (size_t)(GH * M) * 4;
  float* s_g = (float*)(ws + off); off += (size_t)(GH * I) * 4;
  float* s_u = (float*)(ws + off); off += (size_t)(GH * I) * 4;
  float* s_d = (float*)(ws + off); off += (size_t)(GI * H) * 4;
  float* s_h = (float*)(ws + off); off += (size_t)(GI * M) * 4;
  if (ws_size < off) return;

  hipFuncSetAttribute((const void*)gemm_gu_i8,
                      hipFuncAttributeMaxDynamicSharedMemorySize, GU_LDS);
  hipFuncSetAttribute((const void*)gemm_dn_i8,
                      hipFuncAttributeMaxDynamicSharedMemorySize, DN_LDS);

  // 1) int8 group-quant of all inputs/weights in ONE launch
  {
    const long G1 = M * H / 128;
    const long G2 = I * H / 128;
    const long B1 = G1, B2 = G1 + G2, B3 = B2 + G2;
    const long Btot = B3 + H * I / 128;
    qdq8_all<<<dim3((unsigned)((Btot + 7) / 8)), dim3(256), 0, stream>>>(
        x, wg, wu, wd, xq, wgq, wuq, wdq, s_x, s_g, s_u, s_d,
        B1, B2, B3, Btot, (int)GH, (int)GI, (int)M, (int)I, (int)H);
  }

  // 2) fused gate/up int8 GEMM + SwiGLU + hidden quant -> hq, s_h
  {
    const int NBN = (int)GI;                       // 86
    const int grid = (int)(M / 256) * NBN;         // 1376 (%8==0)
    gemm_gu_i8<<<dim3(grid), dim3(512), GU_LDS, stream>>>(
        xq, wgq, wuq, s_x, s_g, s_u, hq, s_h, (int)M, (int)I, (int)H, NBN);
  }
  // 3) down int8 GEMM -> fp32 out
  {
    const int NBN = (int)GH;                       // 32
    const int grid = (int)(M / 256) * NBN;         // 512 (%8==0)
    gemm_dn_i8<<<dim3(grid), dim3(512), DN_LDS, stream>>>(
        hq, wdq, s_h, s_d, out, (int)M, (int)H, (int)I, NBN);
  }
}